// Round 1
// 152.605 us; speedup vs baseline: 1.1288x; 1.1288x over previous
//
#include <hip/hip_runtime.h>

#define BB 4
#define NN 8192
#define QB 32           // queries per block = one 32x32 MFMA tile of queries
#define CAP 96          // survivor capacity per query (slack 6e-3 -> ~23 expected)
#define SLACK 6e-3f     // >= 2*E_filter; covers f16-subnormal-flush worst case

typedef unsigned long long u64;
typedef unsigned int u32;
typedef _Float16 f16x8 __attribute__((ext_vector_type(8)));
typedef float f32x16 __attribute__((ext_vector_type(16)));

__device__ __forceinline__ u64 shfl_xor_u64(u64 v, int m) {
  u32 lo = (u32)v, hi = (u32)(v >> 32);
  lo = (u32)__shfl_xor((int)lo, m, 64);
  hi = (u32)__shfl_xor((int)hi, m, 64);
  return ((u64)hi << 32) | lo;
}
__device__ __forceinline__ u64 shfl_u64(u64 v, int src) {
  u32 lo = (u32)v, hi = (u32)(v >> 32);
  lo = (u32)__shfl((int)lo, src, 64);
  hi = (u32)__shfl((int)hi, src, 64);
  return ((u64)hi << 32) | lo;
}
__device__ __forceinline__ u64 min_u64(u64 a, u64 b) { return a < b ? a : b; }
// force wave-uniform value into an SGPR
__device__ __forceinline__ float rfl(float x) {
  return __int_as_float(__builtin_amdgcn_readfirstlane(__float_as_int(x)));
}

// ascending 64-lane bitonic sort of u64 keys
__device__ __forceinline__ u64 bitonic64(u64 v, int lane) {
#pragma unroll
  for (int k = 2; k <= 64; k <<= 1) {
#pragma unroll
    for (int jm = k >> 1; jm >= 1; jm >>= 1) {
      u64 o = shfl_xor_u64(v, jm);
      bool keepmin = ((lane & jm) == 0) == ((lane & k) == 0);
      u64 mn = min_u64(v, o);
      u64 mx = (v < o) ? o : v;
      v = keepmin ? mn : mx;
    }
  }
  return v;
}

// np-exact distance (bit-matches reference; fma(-2,..) == t-2*inner exactly)
__device__ __forceinline__ float dist_exact(float qx, float qy, float qz, float qw,
                                            float cx, float cy, float cz, float cw) {
#pragma clang fp contract(off)
  float inner = qx * cx;
  inner = inner + qy * cy;
  inner = inner + qz * cz;
  float tt = qw + cw;
  return __builtin_fmaf(-2.0f, inner, tt);
}

// ---- fused: zmat (blocks 0..1023) + coords prep (1024..1151) ----
// coords branch now also emits per-candidate MFMA B-fragment records (32 B):
//   K-slot pairing (A-side query / B-side candidate), c' = -2c:
//   g0: [cxh cxh cxl cyh cyh cyl czh czh]  vs A g0: [qxh qxl qxh qyh qyl qyh qzh qzl]
//   g1: [czl sqh sql 0 0 0 0 0]            vs A g1: [qzh 1 1 0 0 0 0 0]
__global__ void fused_prep_zmat(const float* __restrict__ x, const float* __restrict__ W,
                                const float* __restrict__ coords,
                                float* __restrict__ z, float4* __restrict__ c4p,
                                _Float16* __restrict__ bfr,
                                float* __restrict__ ycoords) {
#pragma clang fp contract(off)
  __shared__ float Ws[64 * 65];
  __shared__ float xs[64 * 32];
  int t = threadIdx.x;
  if (blockIdx.x < 1024) {
    int blk = blockIdx.x;
    int b = blk >> 8;                 // 256 blocks per batch
    int j0 = (blk & 255) * 32;
    for (int r = t; r < 4096; r += 256) Ws[(r >> 6) * 65 + (r & 63)] = W[r];
    const float* xb = x + (size_t)b * 64 * NN;
    for (int r = 0; r < 8; ++r) {
      int idx = t + r * 256;
      int c = idx >> 5, j = idx & 31;
      xs[c * 32 + j] = xb[(size_t)c * NN + j0 + j];
    }
    __syncthreads();
    int o = t & 63, jb = (t >> 6) * 8;
    float acc[8];
#pragma unroll
    for (int m = 0; m < 8; ++m) acc[m] = 0.f;
    for (int c = 0; c < 64; ++c) {
      float w = Ws[o * 65 + c];
#pragma unroll
      for (int m = 0; m < 8; ++m) acc[m] = __builtin_fmaf(w, xs[c * 32 + jb + m], acc[m]);
    }
#pragma unroll
    for (int m = 0; m < 8; ++m)
      z[((size_t)b * NN + j0 + jb + m) * 64 + o] = acc[m];
  } else {
    int t2 = (blockIdx.x - 1024) * 256 + t;   // [0, B*N) candidates
    int b = t2 >> 13;
    int i = t2 & (NN - 1);
    const float* cb = coords + (size_t)b * 3 * NN;
    float cx = cb[i];
    float cy = cb[NN + i];
    float cz = cb[2 * NN + i];
    float sq = (cx * cx + cy * cy) + cz * cz;   // np-exact sequential fp32
    float4 v; v.x = -2.0f * cx; v.y = -2.0f * cy; v.z = -2.0f * cz; v.w = sq;
    c4p[t2] = v;                                 // exact path (recover x via *-0.5)

    // f16 hi/lo split of (-2x,-2y,-2z,sq) for the MFMA filter
    _Float16 xh = (_Float16)v.x, yh = (_Float16)v.y, zh = (_Float16)v.z;
    _Float16 xl = (_Float16)(v.x - (float)xh);
    _Float16 yl = (_Float16)(v.y - (float)yh);
    _Float16 zl = (_Float16)(v.z - (float)zh);
    _Float16 sh = (_Float16)sq;
    _Float16 sl = (_Float16)(sq - (float)sh);
    f16x8 b0, b1;
    b0[0] = xh; b0[1] = xh; b0[2] = xl; b0[3] = yh;
    b0[4] = yh; b0[5] = yl; b0[6] = zh; b0[7] = zh;
    b1[0] = zl; b1[1] = sh; b1[2] = sl;
    b1[3] = (_Float16)0.f; b1[4] = (_Float16)0.f; b1[5] = (_Float16)0.f;
    b1[6] = (_Float16)0.f; b1[7] = (_Float16)0.f;
    f16x8* bp = (f16x8*)bfr;
    bp[(size_t)t2 * 2]     = b0;
    bp[(size_t)t2 * 2 + 1] = b1;

#pragma unroll
    for (int r = 0; r < 3; ++r)                  // flat coords passthrough
      ycoords[r * (BB * NN) + t2] = coords[r * (BB * NN) + t2];
  }
}

// ---- KNN: block = 32 queries, 4 waves split the 8192 candidates.
// Filter d~ = sq_c - 2 q.c computed on the MATRIX pipe (32x32x16 f16 MFMA,
// hi/lo split, 11/16 K-slots). Exact epilogue unchanged -> bit-exact output.
__global__ void __launch_bounds__(256, 4) knn_gather(const float4* __restrict__ c4p,
                                                     const _Float16* __restrict__ bfr,
                                                     const float* __restrict__ z,
                                                     float* __restrict__ y) {
  __shared__ __align__(16) char pool[QB * CAP * 4];   // 12 KB: wmin (passA) then survj (passB)
  __shared__ float TfL[QB];
  __shared__ int scnt[QB];
  __shared__ int sidx[QB][16];
  __shared__ float ys[64][QB + 1];
  float (*wmin)[64] = (float(*)[64])pool;             // [query][64 subset minima]
  u32 (*survj)[CAP] = (u32(*)[CAP])pool;

  int t = threadIdx.x;
  int w = t >> 6, lane = t & 63;
  int lq = lane & 31, lg = lane >> 5;                 // MFMA col / k-group
  int qbase = blockIdx.x * QB;
  int b = qbase >> 13;
  int i0 = qbase & (NN - 1);
  const float4* cp = c4p + (size_t)b * NN;
  int wbase = w * (NN / 4);                           // this wave's candidate range

  if (t < QB) scnt[t] = 0;

  // ---- A fragment: query (l&31), k-slots (l>>5)*8.. (f16 hi/lo split) ----
  float4 qv = cp[i0 + lq];
  float qx = -0.5f * qv.x, qy = -0.5f * qv.y, qz = -0.5f * qv.z;
  _Float16 xh = (_Float16)qx, yh = (_Float16)qy, zh = (_Float16)qz;
  _Float16 xl = (_Float16)(qx - (float)xh);
  _Float16 yl = (_Float16)(qy - (float)yh);
  _Float16 zl = (_Float16)(qz - (float)zh);
  f16x8 af;
  if (lg == 0) {
    af[0] = xh; af[1] = xl; af[2] = xh; af[3] = yh;
    af[4] = yl; af[5] = yh; af[6] = zh; af[7] = zl;
  } else {
    af[0] = zh; af[1] = (_Float16)1.0f; af[2] = (_Float16)1.0f;
    af[3] = (_Float16)0.f; af[4] = (_Float16)0.f; af[5] = (_Float16)0.f;
    af[6] = (_Float16)0.f; af[7] = (_Float16)0.f;
  }

  f32x16 zzz, mn;
#pragma unroll
  for (int r = 0; r < 16; ++r) { zzz[r] = 0.f; mn[r] = 3.402823466e+38f; }

  // per-lane B-fragment stream: candidate = wbase + tt*32 + lq, group lg
  const f16x8* lp = (const f16x8*)bfr + (((size_t)b * NN + wbase + lq) * 2 + lg);

  // ---- pass A: running min of d~ over this wave's 2048 candidates ----
  // D[row=query][col=cand]: col = lane&31, row = (reg&3)+8*(reg>>2)+4*(lane>>5)
#pragma unroll 4
  for (int tt = 0; tt < 64; ++tt) {
    f16x8 bc = lp[tt * 64];
    f32x16 d = __builtin_amdgcn_mfma_f32_32x32x16_f16(af, bc, zzz, 0, 0, 0);
#pragma unroll
    for (int r = 0; r < 16; ++r) mn[r] = fminf(mn[r], d[r]);
  }

  // fold lane pairs (l, l^16): 16 disjoint 128-cand subset-minima per wave/query
#pragma unroll
  for (int r = 0; r < 16; ++r) {
    float m2 = fminf(mn[r], __shfl_xor(mn[r], 16, 64));
    int q = (r & 3) + 8 * (r >> 2) + 4 * lg;
    if (lq < 16) wmin[q][w * 16 + lq] = m2;
  }
  __syncthreads();

  // ---- threshold: 16th smallest of 64 subset-minima + slack (valid bound) ----
#pragma unroll 1
  for (int qi = 0; qi < 8; ++qi) {
    int q = w * 8 + qi;
    float v = wmin[q][lane];
#pragma unroll
    for (int k = 2; k <= 64; k <<= 1) {
#pragma unroll
      for (int jm = k >> 1; jm >= 1; jm >>= 1) {
        float o = __shfl_xor(v, jm, 64);
        bool keepmin = ((lane & jm) == 0) == ((lane & k) == 0);
        v = keepmin ? fminf(v, o) : fmaxf(v, o);
      }
    }
    if (lane == 15) TfL[q] = v + SLACK;   // rank-15 = 16th smallest
  }
  __syncthreads();

  // ---- pass B: identical MFMA values; fire survivor indices ----
  float tf[16];
#pragma unroll
  for (int r = 0; r < 16; ++r) tf[r] = TfL[(r & 3) + 8 * (r >> 2) + 4 * lg];

#pragma unroll 2
  for (int tt = 0; tt < 64; ++tt) {
    f16x8 bc = lp[tt * 64];
    f32x16 d = __builtin_amdgcn_mfma_f32_32x32x16_f16(af, bc, zzz, 0, 0, 0);
    int cand = wbase + tt * 32 + lq;
#pragma unroll
    for (int r = 0; r < 16; ++r) {
      if (d[r] <= tf[r]) {
        int q = (r & 3) + 8 * (r >> 2) + 4 * lg;
        int pos = atomicAdd(&scnt[q], 1);
        if (pos < CAP) survj[q][pos] = (u32)cand;
      }
    }
  }
  __syncthreads();

  // ---- epilogue: np-exact keys for survivors, u64 bitonic, gather ----
  const float* zb = z + (size_t)b * NN * 64;
#pragma unroll 1
  for (int qi = 0; qi < 8; ++qi) {
    int q = w * 8 + qi;
    int n = scnt[q]; if (n > CAP) n = CAP;
    float4 qq = cp[i0 + q];
    float eqx = rfl(-0.5f * qq.x), eqy = rfl(-0.5f * qq.y);
    float eqz = rfl(-0.5f * qq.z), eqw = rfl(qq.w);
    u64 v = ~0ull;
    if (lane < n) {
      int c = (int)survj[q][lane];
      float4 cj = cp[c];                         // scattered L2 re-load (few)
      float de = dist_exact(eqx, eqy, eqz, eqw,
                            -0.5f * cj.x, -0.5f * cj.y, -0.5f * cj.z, cj.w);
      u32 f = __float_as_uint(de);
      u32 m32 = f ^ ((u32)(((int)f) >> 31) | 0x80000000u);
      v = ((u64)m32 << 32) | (u32)c;
    }
    v = bitonic64(v, lane);
    if (n > 64) {                                // rare overflow chunk (n<=96)
      u64 v2 = ~0ull;
      if (lane + 64 < n) {
        int c = (int)survj[q][lane + 64];
        float4 cj = cp[c];
        float de = dist_exact(eqx, eqy, eqz, eqw,
                              -0.5f * cj.x, -0.5f * cj.y, -0.5f * cj.z, cj.w);
        u32 f = __float_as_uint(de);
        u32 m32 = f ^ ((u32)(((int)f) >> 31) | 0x80000000u);
        v2 = ((u64)m32 << 32) | (u32)c;
      }
      v2 = bitonic64(v2, lane);
      // 16 smallest of union(top16 chunk1, top16 chunk2)
      u64 vm = (lane < 16) ? v : ((lane < 32) ? shfl_u64(v2, lane - 16) : ~0ull);
      v = bitonic64(vm, lane);
    }
    if (lane < 16) sidx[q][lane] = (int)(v & 0xFFFFFFFFull);
  }

#pragma unroll 1
  for (int qi = 0; qi < 8; ++qi) {
    int q = w * 8 + qi;
    const int* id = sidx[q];                     // same-wave LDS, program-order safe
    float m = -3.402823466e+38f;
#pragma unroll
    for (int k = 0; k < 16; ++k)
      m = fmaxf(m, zb[(size_t)id[k] * 64 + lane]);   // coalesced 256B row
    ys[lane][q] = m;
  }
  __syncthreads();   // transpose for coalesced store
#pragma unroll
  for (int r = 0; r < 8; ++r) {
    int e = r * 256 + t;
    int o = e >> 5, ql = e & 31;
    y[((size_t)b * 64 + o) * NN + i0 + ql] = ys[o][ql];
  }
}

extern "C" void kernel_launch(void* const* d_in, const int* in_sizes, int n_in,
                              void* d_out, int out_size, void* d_ws, size_t ws_size,
                              hipStream_t stream) {
  const float* x      = (const float*)d_in[0];   // [B,64,N]
  const float* coords = (const float*)d_in[1];   // [B,3,N]
  const float* W      = (const float*)d_in[2];   // [64,64]
  float* y = (float*)d_out;                      // [B,64,N] then coords

  char* ws = (char*)d_ws;
  float4*   c4p = (float4*)ws;                   // 512 KB exact (-2x,-2y,-2z,sq)
  _Float16* bfr = (_Float16*)(ws + (512u << 10));// 1 MB  MFMA B-fragments (32 B/cand)
  float*    z   = (float*)(ws + (2u << 20));     // 8 MB  zmat

  float* ycoords = y + (size_t)BB * 64 * NN;

  fused_prep_zmat<<<1024 + 128, 256, 0, stream>>>(x, W, coords, z, c4p, bfr, ycoords);
  knn_gather<<<BB * NN / QB, 256, 0, stream>>>(c4p, bfr, z, y);
}

// Round 2
// 137.741 us; speedup vs baseline: 1.2506x; 1.1079x over previous
//
#include <hip/hip_runtime.h>

#define BB 4
#define NN 8192
#define QB 32           // queries per block = one 32x32 MFMA tile of queries
#define NW 8            // waves per block; each scans NN/NW = 1024 candidates
#define CAP 96          // survivor capacity per query (slack 6e-3 -> ~23 expected)
#define SLACK 6e-3f     // >= 2*E_filter; covers f16-subnormal-flush worst case

typedef unsigned long long u64;
typedef unsigned int u32;
typedef _Float16 f16x8 __attribute__((ext_vector_type(8)));
typedef float f32x16 __attribute__((ext_vector_type(16)));

__device__ __forceinline__ u64 shfl_xor_u64(u64 v, int m) {
  u32 lo = (u32)v, hi = (u32)(v >> 32);
  lo = (u32)__shfl_xor((int)lo, m, 64);
  hi = (u32)__shfl_xor((int)hi, m, 64);
  return ((u64)hi << 32) | lo;
}
__device__ __forceinline__ u64 shfl_u64(u64 v, int src) {
  u32 lo = (u32)v, hi = (u32)(v >> 32);
  lo = (u32)__shfl((int)lo, src, 64);
  hi = (u32)__shfl((int)hi, src, 64);
  return ((u64)hi << 32) | lo;
}
__device__ __forceinline__ u64 min_u64(u64 a, u64 b) { return a < b ? a : b; }
// force wave-uniform value into an SGPR
__device__ __forceinline__ float rfl(float x) {
  return __int_as_float(__builtin_amdgcn_readfirstlane(__float_as_int(x)));
}

// ascending 64-lane bitonic sort of u64 keys
__device__ __forceinline__ u64 bitonic64(u64 v, int lane) {
#pragma unroll
  for (int k = 2; k <= 64; k <<= 1) {
#pragma unroll
    for (int jm = k >> 1; jm >= 1; jm >>= 1) {
      u64 o = shfl_xor_u64(v, jm);
      bool keepmin = ((lane & jm) == 0) == ((lane & k) == 0);
      u64 mn = min_u64(v, o);
      u64 mx = (v < o) ? o : v;
      v = keepmin ? mn : mx;
    }
  }
  return v;
}

// np-exact distance (bit-matches reference; fma(-2,..) == t-2*inner exactly)
__device__ __forceinline__ float dist_exact(float qx, float qy, float qz, float qw,
                                            float cx, float cy, float cz, float cw) {
#pragma clang fp contract(off)
  float inner = qx * cx;
  inner = inner + qy * cy;
  inner = inner + qz * cz;
  float tt = qw + cw;
  return __builtin_fmaf(-2.0f, inner, tt);
}

// ---- fused: zmat (blocks 0..1023) + coords prep (1024..1151) ----
// coords branch emits per-candidate MFMA B-fragment records (32 B):
//   g0: [cxh cxh cxl cyh cyh cyl czh czh]  vs A g0: [qxh qxl qxh qyh qyl qyh qzh qzl]
//   g1: [czl sqh sql 0 0 0 0 0]            vs A g1: [qzh 1 1 0 0 0 0 0]
__global__ void fused_prep_zmat(const float* __restrict__ x, const float* __restrict__ W,
                                const float* __restrict__ coords,
                                float* __restrict__ z, float4* __restrict__ c4p,
                                _Float16* __restrict__ bfr,
                                float* __restrict__ ycoords) {
#pragma clang fp contract(off)
  __shared__ float Ws[64 * 65];
  __shared__ float xs[64 * 32];
  int t = threadIdx.x;
  if (blockIdx.x < 1024) {
    int blk = blockIdx.x;
    int b = blk >> 8;                 // 256 blocks per batch
    int j0 = (blk & 255) * 32;
    for (int r = t; r < 4096; r += 256) Ws[(r >> 6) * 65 + (r & 63)] = W[r];
    const float* xb = x + (size_t)b * 64 * NN;
    for (int r = 0; r < 8; ++r) {
      int idx = t + r * 256;
      int c = idx >> 5, j = idx & 31;
      xs[c * 32 + j] = xb[(size_t)c * NN + j0 + j];
    }
    __syncthreads();
    int o = t & 63, jb = (t >> 6) * 8;
    float acc[8];
#pragma unroll
    for (int m = 0; m < 8; ++m) acc[m] = 0.f;
    for (int c = 0; c < 64; ++c) {
      float w = Ws[o * 65 + c];
#pragma unroll
      for (int m = 0; m < 8; ++m) acc[m] = __builtin_fmaf(w, xs[c * 32 + jb + m], acc[m]);
    }
#pragma unroll
    for (int m = 0; m < 8; ++m)
      z[((size_t)b * NN + j0 + jb + m) * 64 + o] = acc[m];
  } else {
    int t2 = (blockIdx.x - 1024) * 256 + t;   // [0, B*N) candidates
    int b = t2 >> 13;
    int i = t2 & (NN - 1);
    const float* cb = coords + (size_t)b * 3 * NN;
    float cx = cb[i];
    float cy = cb[NN + i];
    float cz = cb[2 * NN + i];
    float sq = (cx * cx + cy * cy) + cz * cz;   // np-exact sequential fp32
    float4 v; v.x = -2.0f * cx; v.y = -2.0f * cy; v.z = -2.0f * cz; v.w = sq;
    c4p[t2] = v;                                 // exact path (recover x via *-0.5)

    // f16 hi/lo split of (-2x,-2y,-2z,sq) for the MFMA filter
    _Float16 xh = (_Float16)v.x, yh = (_Float16)v.y, zh = (_Float16)v.z;
    _Float16 xl = (_Float16)(v.x - (float)xh);
    _Float16 yl = (_Float16)(v.y - (float)yh);
    _Float16 zl = (_Float16)(v.z - (float)zh);
    _Float16 sh = (_Float16)sq;
    _Float16 sl = (_Float16)(sq - (float)sh);
    f16x8 b0, b1;
    b0[0] = xh; b0[1] = xh; b0[2] = xl; b0[3] = yh;
    b0[4] = yh; b0[5] = yl; b0[6] = zh; b0[7] = zh;
    b1[0] = zl; b1[1] = sh; b1[2] = sl;
    b1[3] = (_Float16)0.f; b1[4] = (_Float16)0.f; b1[5] = (_Float16)0.f;
    b1[6] = (_Float16)0.f; b1[7] = (_Float16)0.f;
    f16x8* bp = (f16x8*)bfr;
    bp[(size_t)t2 * 2]     = b0;
    bp[(size_t)t2 * 2 + 1] = b1;

#pragma unroll
    for (int r = 0; r < 3; ++r)                  // flat coords passthrough
      ycoords[r * (BB * NN) + t2] = coords[r * (BB * NN) + t2];
  }
}

// ---- KNN: block = 32 queries x 8 waves; wave scans 1024 candidates (32 tiles).
// 8 waves/SIMD (grid 1024 = 4 blocks/CU) for latency hiding; VGPR capped at 64.
__global__ void __launch_bounds__(512, 8) knn_gather(const float4* __restrict__ c4p,
                                                     const _Float16* __restrict__ bfr,
                                                     const float* __restrict__ z,
                                                     float* __restrict__ y) {
  __shared__ __align__(16) char pool[QB * 128 * 4];   // 16 KB: wmin (passA) then survj (passB)
  __shared__ float TfL[QB];
  __shared__ int scnt[QB];
  __shared__ int sidx[QB][16];
  __shared__ float ys[64][QB + 1];
  float (*wmin)[128] = (float(*)[128])pool;           // [query][128 subset minima]
  u32 (*survj)[CAP] = (u32(*)[CAP])pool;

  int t = threadIdx.x;
  int w = t >> 6, lane = t & 63;
  int lq = lane & 31, lg = lane >> 5;                 // MFMA col / k-group
  int lg4 = lg << 2;
  int qbase = blockIdx.x * QB;
  int b = qbase >> 13;
  int i0 = qbase & (NN - 1);
  const float4* cp = c4p + (size_t)b * NN;
  int wbase = w * (NN / NW);                          // this wave's candidate range

  if (t < QB) scnt[t] = 0;

  // ---- A fragment: query (l&31), k-slots (l>>5)*8.. (f16 hi/lo split) ----
  float4 qv = cp[i0 + lq];
  float qx = -0.5f * qv.x, qy = -0.5f * qv.y, qz = -0.5f * qv.z;
  _Float16 xh = (_Float16)qx, yh = (_Float16)qy, zh = (_Float16)qz;
  _Float16 xl = (_Float16)(qx - (float)xh);
  _Float16 yl = (_Float16)(qy - (float)yh);
  _Float16 zl = (_Float16)(qz - (float)zh);
  f16x8 af;
  if (lg == 0) {
    af[0] = xh; af[1] = xl; af[2] = xh; af[3] = yh;
    af[4] = yl; af[5] = yh; af[6] = zh; af[7] = zl;
  } else {
    af[0] = zh; af[1] = (_Float16)1.0f; af[2] = (_Float16)1.0f;
    af[3] = (_Float16)0.f; af[4] = (_Float16)0.f; af[5] = (_Float16)0.f;
    af[6] = (_Float16)0.f; af[7] = (_Float16)0.f;
  }

  f32x16 zzz, mn;
#pragma unroll
  for (int r = 0; r < 16; ++r) { zzz[r] = 0.f; mn[r] = 3.402823466e+38f; }

  // per-lane B-fragment stream: candidate = wbase + tt*32 + lq, group lg
  const f16x8* lp = (const f16x8*)bfr + (((size_t)b * NN + wbase + lq) * 2 + lg);

  // ---- pass A: running min of d~ over this wave's 1024 candidates ----
  // D[row=query][col=cand]: col = lane&31, row = (reg&3)+8*(reg>>2)+4*(lane>>5)
#pragma unroll 2
  for (int tt = 0; tt < 32; tt += 2) {
    f16x8 bc0 = lp[tt * 64];
    f16x8 bc1 = lp[(tt + 1) * 64];
    f32x16 d0 = __builtin_amdgcn_mfma_f32_32x32x16_f16(af, bc0, zzz, 0, 0, 0);
    f32x16 d1 = __builtin_amdgcn_mfma_f32_32x32x16_f16(af, bc1, zzz, 0, 0, 0);
#pragma unroll
    for (int r = 0; r < 16; ++r) mn[r] = fminf(fminf(mn[r], d0[r]), d1[r]);  // v_min3
  }

  // fold lane pairs (l, l^16): 16 disjoint 64-cand subset-minima per wave/query
#pragma unroll
  for (int r = 0; r < 16; ++r) {
    float m2 = fminf(mn[r], __shfl_xor(mn[r], 16, 64));
    int q = (r & 3) + 8 * (r >> 2) + lg4;
    if (lq < 16) wmin[q][w * 16 + lq] = m2;
  }
  __syncthreads();

  // ---- threshold: pre-min pairs -> 64 subsets of 128 cands; 16th smallest + slack ----
#pragma unroll 1
  for (int qi = 0; qi < QB / NW; ++qi) {
    int q = w * (QB / NW) + qi;
    float v = fminf(wmin[q][2 * lane], wmin[q][2 * lane + 1]);
#pragma unroll
    for (int k = 2; k <= 64; k <<= 1) {
#pragma unroll
      for (int jm = k >> 1; jm >= 1; jm >>= 1) {
        float o = __shfl_xor(v, jm, 64);
        bool keepmin = ((lane & jm) == 0) == ((lane & k) == 0);
        v = keepmin ? fminf(v, o) : fmaxf(v, o);
      }
    }
    if (lane == 15) TfL[q] = v + SLACK;   // rank-15 = 16th smallest
  }
  __syncthreads();

  // ---- pass B: same MFMA with C = -tf; fire iff d' <= 0 ----
  f32x16 mc;
#pragma unroll
  for (int r = 0; r < 16; ++r) mc[r] = -TfL[(r & 3) + 8 * (r >> 2) + lg4];

#pragma unroll 2
  for (int tt = 0; tt < 32; ++tt) {
    f16x8 bc = lp[tt * 64];
    f32x16 d = __builtin_amdgcn_mfma_f32_32x32x16_f16(af, bc, mc, 0, 0, 0);
    int cand = wbase + tt * 32 + lq;
#pragma unroll
    for (int r = 0; r < 16; ++r) {
      if (d[r] <= 0.f) {
        int q = (r & 3) + 8 * (r >> 2) + lg4;
        int pos = atomicAdd(&scnt[q], 1);
        if (pos < CAP) survj[q][pos] = (u32)cand;
      }
    }
  }
  __syncthreads();

  // ---- epilogue: np-exact keys for survivors, u64 bitonic, gather ----
  const float* zb = z + (size_t)b * NN * 64;
#pragma unroll 1
  for (int qi = 0; qi < QB / NW; ++qi) {
    int q = w * (QB / NW) + qi;
    int n = scnt[q]; if (n > CAP) n = CAP;
    float4 qq = cp[i0 + q];
    float eqx = rfl(-0.5f * qq.x), eqy = rfl(-0.5f * qq.y);
    float eqz = rfl(-0.5f * qq.z), eqw = rfl(qq.w);
    u64 v = ~0ull;
    if (lane < n) {
      int c = (int)survj[q][lane];
      float4 cj = cp[c];                         // scattered L2 re-load (few)
      float de = dist_exact(eqx, eqy, eqz, eqw,
                            -0.5f * cj.x, -0.5f * cj.y, -0.5f * cj.z, cj.w);
      u32 f = __float_as_uint(de);
      u32 m32 = f ^ ((u32)(((int)f) >> 31) | 0x80000000u);
      v = ((u64)m32 << 32) | (u32)c;
    }
    v = bitonic64(v, lane);
    if (n > 64) {                                // rare overflow chunk (n<=96)
      u64 v2 = ~0ull;
      if (lane + 64 < n) {
        int c = (int)survj[q][lane + 64];
        float4 cj = cp[c];
        float de = dist_exact(eqx, eqy, eqz, eqw,
                              -0.5f * cj.x, -0.5f * cj.y, -0.5f * cj.z, cj.w);
        u32 f = __float_as_uint(de);
        u32 m32 = f ^ ((u32)(((int)f) >> 31) | 0x80000000u);
        v2 = ((u64)m32 << 32) | (u32)c;
      }
      v2 = bitonic64(v2, lane);
      // 16 smallest of union(top16 chunk1, top16 chunk2)
      u64 vm = (lane < 16) ? v : ((lane < 32) ? shfl_u64(v2, lane - 16) : ~0ull);
      v = bitonic64(vm, lane);
    }
    if (lane < 16) sidx[q][lane] = (int)(v & 0xFFFFFFFFull);
  }

#pragma unroll 1
  for (int qi = 0; qi < QB / NW; ++qi) {
    int q = w * (QB / NW) + qi;
    const int* id = sidx[q];                     // same-wave LDS, program-order safe
    float m = -3.402823466e+38f;
#pragma unroll
    for (int k = 0; k < 16; ++k)
      m = fmaxf(m, zb[(size_t)id[k] * 64 + lane]);   // coalesced 256B row
    ys[lane][q] = m;
  }
  __syncthreads();   // transpose for coalesced float4 store
  {
    int o = t >> 3;                // 512 threads: 64 rows x 8 float4
    int ql0 = (t & 7) * 4;
    float4 vv;
    vv.x = ys[o][ql0]; vv.y = ys[o][ql0 + 1];
    vv.z = ys[o][ql0 + 2]; vv.w = ys[o][ql0 + 3];
    *(float4*)&y[((size_t)b * 64 + o) * NN + i0 + ql0] = vv;
  }
}

extern "C" void kernel_launch(void* const* d_in, const int* in_sizes, int n_in,
                              void* d_out, int out_size, void* d_ws, size_t ws_size,
                              hipStream_t stream) {
  const float* x      = (const float*)d_in[0];   // [B,64,N]
  const float* coords = (const float*)d_in[1];   // [B,3,N]
  const float* W      = (const float*)d_in[2];   // [64,64]
  float* y = (float*)d_out;                      // [B,64,N] then coords

  char* ws = (char*)d_ws;
  float4*   c4p = (float4*)ws;                   // 512 KB exact (-2x,-2y,-2z,sq)
  _Float16* bfr = (_Float16*)(ws + (512u << 10));// 1 MB  MFMA B-fragments (32 B/cand)
  float*    z   = (float*)(ws + (2u << 20));     // 8 MB  zmat

  float* ycoords = y + (size_t)BB * 64 * NN;

  fused_prep_zmat<<<1024 + 128, 256, 0, stream>>>(x, W, coords, z, c4p, bfr, ycoords);
  knn_gather<<<BB * NN / QB, 512, 0, stream>>>(c4p, bfr, z, y);
}

// Round 4
// 136.868 us; speedup vs baseline: 1.2585x; 1.0064x over previous
//
#include <hip/hip_runtime.h>

#define BB 4
#define NN 8192
#define QB 32           // queries per block = one 32x32 MFMA tile of queries
#define NW 8            // waves per block; each scans NN/NW = 1024 candidates
#define CAP 96          // survivor capacity (half-sample threshold -> ~42 expected)
#define SLACK 6e-3f     // >= 2*E_filter; covers f16-subnormal-flush worst case

typedef unsigned long long u64;
typedef unsigned int u32;
typedef _Float16 f16x8 __attribute__((ext_vector_type(8)));
typedef float f32x16 __attribute__((ext_vector_type(16)));

__device__ __forceinline__ u64 shfl_xor_u64(u64 v, int m) {
  u32 lo = (u32)v, hi = (u32)(v >> 32);
  lo = (u32)__shfl_xor((int)lo, m, 64);
  hi = (u32)__shfl_xor((int)hi, m, 64);
  return ((u64)hi << 32) | lo;
}
__device__ __forceinline__ u64 shfl_u64(u64 v, int src) {
  u32 lo = (u32)v, hi = (u32)(v >> 32);
  lo = (u32)__shfl((int)lo, src, 64);
  hi = (u32)__shfl((int)hi, src, 64);
  return ((u64)hi << 32) | lo;
}
__device__ __forceinline__ u64 min_u64(u64 a, u64 b) { return a < b ? a : b; }
// force wave-uniform value into an SGPR
__device__ __forceinline__ float rfl(float x) {
  return __int_as_float(__builtin_amdgcn_readfirstlane(__float_as_int(x)));
}

// ascending 64-lane bitonic sort of u64 keys
__device__ __forceinline__ u64 bitonic64(u64 v, int lane) {
#pragma unroll
  for (int k = 2; k <= 64; k <<= 1) {
#pragma unroll
    for (int jm = k >> 1; jm >= 1; jm >>= 1) {
      u64 o = shfl_xor_u64(v, jm);
      bool keepmin = ((lane & jm) == 0) == ((lane & k) == 0);
      u64 mn = min_u64(v, o);
      u64 mx = (v < o) ? o : v;
      v = keepmin ? mn : mx;
    }
  }
  return v;
}

// np-exact distance (bit-matches reference; fma(-2,..) == t-2*inner exactly)
__device__ __forceinline__ float dist_exact(float qx, float qy, float qz, float qw,
                                            float cx, float cy, float cz, float cw) {
#pragma clang fp contract(off)
  float inner = qx * cx;
  inner = inner + qy * cy;
  inner = inner + qz * cz;
  float tt = qw + cw;
  return __builtin_fmaf(-2.0f, inner, tt);
}

// ---- fused: zmat (blocks 0..511, register-blocked 4o x 4j) + coords prep (512..639) ----
// zmat: per c only 2 ds_read_b128 per 16 fma. Ascending-c fma chain -> z bit-identical.
__global__ void __launch_bounds__(256, 4) fused_prep_zmat(
    const float* __restrict__ x, const float* __restrict__ W,
    const float* __restrict__ coords,
    float* __restrict__ z, float4* __restrict__ c4p,
    _Float16* __restrict__ bfr,
    float* __restrict__ ycoords) {
#pragma clang fp contract(off)
  __shared__ float Wst[64 * 68];   // [c][o], pitch 68 (16B-aligned rows, bank-spread)
  __shared__ float xs[64 * 64];    // [c][j]
  int t = threadIdx.x;
  if (blockIdx.x < 512) {
    int blk = blockIdx.x;
    int b = blk >> 7;                 // 128 blocks per batch
    int j0 = (blk & 127) * 64;
    for (int r = t; r < 4096; r += 256) Wst[(r & 63) * 68 + (r >> 6)] = W[r];
    const float* xb = x + (size_t)b * 64 * NN;
#pragma unroll
    for (int r = 0; r < 16; ++r) {
      int idx = t + r * 256;
      int c = idx >> 6, j = idx & 63;
      xs[c * 64 + j] = xb[(size_t)c * NN + j0 + j];
    }
    __syncthreads();
    int o0 = (t & 15) * 4, jb = (t >> 4) * 4;
    float4 a0 = {0.f, 0.f, 0.f, 0.f}, a1 = a0, a2 = a0, a3 = a0;  // a[jj].{oi}
#pragma unroll 4
    for (int c = 0; c < 64; ++c) {
      float4 w4 = *(const float4*)&Wst[c * 68 + o0];
      float4 x4 = *(const float4*)&xs[c * 64 + jb];
      a0.x = __builtin_fmaf(w4.x, x4.x, a0.x);
      a0.y = __builtin_fmaf(w4.y, x4.x, a0.y);
      a0.z = __builtin_fmaf(w4.z, x4.x, a0.z);
      a0.w = __builtin_fmaf(w4.w, x4.x, a0.w);
      a1.x = __builtin_fmaf(w4.x, x4.y, a1.x);
      a1.y = __builtin_fmaf(w4.y, x4.y, a1.y);
      a1.z = __builtin_fmaf(w4.z, x4.y, a1.z);
      a1.w = __builtin_fmaf(w4.w, x4.y, a1.w);
      a2.x = __builtin_fmaf(w4.x, x4.z, a2.x);
      a2.y = __builtin_fmaf(w4.y, x4.z, a2.y);
      a2.z = __builtin_fmaf(w4.z, x4.z, a2.z);
      a2.w = __builtin_fmaf(w4.w, x4.z, a2.w);
      a3.x = __builtin_fmaf(w4.x, x4.w, a3.x);
      a3.y = __builtin_fmaf(w4.y, x4.w, a3.y);
      a3.z = __builtin_fmaf(w4.z, x4.w, a3.z);
      a3.w = __builtin_fmaf(w4.w, x4.w, a3.w);
    }
    size_t rbase = (size_t)b * NN + j0 + jb;
    *(float4*)&z[(rbase + 0) * 64 + o0] = a0;
    *(float4*)&z[(rbase + 1) * 64 + o0] = a1;
    *(float4*)&z[(rbase + 2) * 64 + o0] = a2;
    *(float4*)&z[(rbase + 3) * 64 + o0] = a3;
  } else {
    int t2 = (blockIdx.x - 512) * 256 + t;   // [0, B*N) candidates
    int b = t2 >> 13;
    int i = t2 & (NN - 1);
    const float* cb = coords + (size_t)b * 3 * NN;
    float cx = cb[i];
    float cy = cb[NN + i];
    float cz = cb[2 * NN + i];
    float sq = (cx * cx + cy * cy) + cz * cz;   // np-exact sequential fp32
    float4 v; v.x = -2.0f * cx; v.y = -2.0f * cy; v.z = -2.0f * cz; v.w = sq;
    c4p[t2] = v;                                 // exact path (recover x via *-0.5)

    // f16 hi/lo split of (-2x,-2y,-2z,sq) for the MFMA filter
    _Float16 xh = (_Float16)v.x, yh = (_Float16)v.y, zh = (_Float16)v.z;
    _Float16 xl = (_Float16)(v.x - (float)xh);
    _Float16 yl = (_Float16)(v.y - (float)yh);
    _Float16 zl = (_Float16)(v.z - (float)zh);
    _Float16 sh = (_Float16)sq;
    _Float16 sl = (_Float16)(sq - (float)sh);
    f16x8 b0, b1;
    b0[0] = xh; b0[1] = xh; b0[2] = xl; b0[3] = yh;
    b0[4] = yh; b0[5] = yl; b0[6] = zh; b0[7] = zh;
    b1[0] = zl; b1[1] = sh; b1[2] = sl;
    b1[3] = (_Float16)0.f; b1[4] = (_Float16)0.f; b1[5] = (_Float16)0.f;
    b1[6] = (_Float16)0.f; b1[7] = (_Float16)0.f;
    f16x8* bp = (f16x8*)bfr;
    bp[(size_t)t2 * 2]     = b0;
    bp[(size_t)t2 * 2 + 1] = b1;

#pragma unroll
    for (int r = 0; r < 3; ++r)                  // flat coords passthrough
      ycoords[r * (BB * NN) + t2] = coords[r * (BB * NN) + t2];
  }
}

// ---- KNN: block = 32 queries x 8 waves; wave scans 1024 candidates (32 tiles).
// Pass A over the wave's FIRST 16 tiles (4096-cand subsample across the block):
// 16th-smallest of 64 subset-minima (= 16 distinct actual distances) is a valid
// upper bound on d16 of the full set. Survivors ~42 mean; n>64 overflow path is
// now EXERCISED -> R3 bug: divergent __shfl from inactive lanes (UB, returns 0)
// corrupted the 2-chunk merge. Fixed: hoist the shfl to uniform execution.
__global__ void __launch_bounds__(512, 8) knn_gather(const float4* __restrict__ c4p,
                                                     const _Float16* __restrict__ bfr,
                                                     const float* __restrict__ z,
                                                     float* __restrict__ y) {
  __shared__ __align__(16) char pool[QB * 128 * 4];   // 16 KB: wmin (passA) then survj (passB)
  __shared__ float TfL[QB];
  __shared__ int scnt[QB];
  __shared__ int sidx[QB][16];
  __shared__ float ys[64][QB + 1];
  float (*wmin)[128] = (float(*)[128])pool;           // [query][128 subset minima]
  u32 (*survj)[CAP] = (u32(*)[CAP])pool;

  int t = threadIdx.x;
  int w = t >> 6, lane = t & 63;
  int lq = lane & 31, lg = lane >> 5;                 // MFMA col / k-group
  int lg4 = lg << 2;
  int qbase = blockIdx.x * QB;
  int b = qbase >> 13;
  int i0 = qbase & (NN - 1);
  const float4* cp = c4p + (size_t)b * NN;
  int wbase = w * (NN / NW);                          // this wave's candidate range

  if (t < QB) scnt[t] = 0;

  // ---- A fragment: query (l&31), k-slots (l>>5)*8.. (f16 hi/lo split) ----
  float4 qv = cp[i0 + lq];
  float qx = -0.5f * qv.x, qy = -0.5f * qv.y, qz = -0.5f * qv.z;
  _Float16 xh = (_Float16)qx, yh = (_Float16)qy, zh = (_Float16)qz;
  _Float16 xl = (_Float16)(qx - (float)xh);
  _Float16 yl = (_Float16)(qy - (float)yh);
  _Float16 zl = (_Float16)(qz - (float)zh);
  f16x8 af;
  if (lg == 0) {
    af[0] = xh; af[1] = xl; af[2] = xh; af[3] = yh;
    af[4] = yl; af[5] = yh; af[6] = zh; af[7] = zl;
  } else {
    af[0] = zh; af[1] = (_Float16)1.0f; af[2] = (_Float16)1.0f;
    af[3] = (_Float16)0.f; af[4] = (_Float16)0.f; af[5] = (_Float16)0.f;
    af[6] = (_Float16)0.f; af[7] = (_Float16)0.f;
  }

  f32x16 zzz, mn;
#pragma unroll
  for (int r = 0; r < 16; ++r) { zzz[r] = 0.f; mn[r] = 3.402823466e+38f; }

  // per-lane B-fragment stream: candidate = wbase + tt*32 + lq, group lg
  const f16x8* lp = (const f16x8*)bfr + (((size_t)b * NN + wbase + lq) * 2 + lg);

  // ---- pass A (half-sample): running min of d~ over first 512 of 1024 cands ----
  // D[row=query][col=cand]: col = lane&31, row = (reg&3)+8*(reg>>2)+4*(lane>>5)
#pragma unroll 2
  for (int tt = 0; tt < 16; tt += 2) {
    f16x8 bc0 = lp[tt * 64];
    f16x8 bc1 = lp[(tt + 1) * 64];
    f32x16 d0 = __builtin_amdgcn_mfma_f32_32x32x16_f16(af, bc0, zzz, 0, 0, 0);
    f32x16 d1 = __builtin_amdgcn_mfma_f32_32x32x16_f16(af, bc1, zzz, 0, 0, 0);
#pragma unroll
    for (int r = 0; r < 16; ++r) mn[r] = fminf(fminf(mn[r], d0[r]), d1[r]);  // v_min3
  }

  // fold lane pairs (l, l^16): 16 disjoint 32-cand subset-minima per wave/query
#pragma unroll
  for (int r = 0; r < 16; ++r) {
    float m2 = fminf(mn[r], __shfl_xor(mn[r], 16, 64));
    int q = (r & 3) + 8 * (r >> 2) + lg4;
    if (lq < 16) wmin[q][w * 16 + lq] = m2;
  }
  __syncthreads();

  // ---- threshold: pre-min pairs -> 64 subsets of 64 cands; 16th smallest + slack ----
#pragma unroll 1
  for (int qi = 0; qi < QB / NW; ++qi) {
    int q = w * (QB / NW) + qi;
    float v = fminf(wmin[q][2 * lane], wmin[q][2 * lane + 1]);
#pragma unroll
    for (int k = 2; k <= 64; k <<= 1) {
#pragma unroll
      for (int jm = k >> 1; jm >= 1; jm >>= 1) {
        float o = __shfl_xor(v, jm, 64);
        bool keepmin = ((lane & jm) == 0) == ((lane & k) == 0);
        v = keepmin ? fminf(v, o) : fmaxf(v, o);
      }
    }
    if (lane == 15) TfL[q] = v + SLACK;   // rank-15 = 16th smallest
  }
  __syncthreads();

  // ---- pass B: same MFMA with C = -tf; fire iff d' <= 0 ----
  f32x16 mc;
#pragma unroll
  for (int r = 0; r < 16; ++r) mc[r] = -TfL[(r & 3) + 8 * (r >> 2) + lg4];

#pragma unroll 4
  for (int tt = 0; tt < 32; ++tt) {
    f16x8 bc = lp[tt * 64];
    f32x16 d = __builtin_amdgcn_mfma_f32_32x32x16_f16(af, bc, mc, 0, 0, 0);
    int cand = wbase + tt * 32 + lq;
#pragma unroll
    for (int r = 0; r < 16; ++r) {
      if (d[r] <= 0.f) {
        int q = (r & 3) + 8 * (r >> 2) + lg4;
        int pos = atomicAdd(&scnt[q], 1);
        if (pos < CAP) survj[q][pos] = (u32)cand;
      }
    }
  }
  __syncthreads();

  // ---- epilogue: np-exact keys for survivors, u64 bitonic, gather ----
  const float* zb = z + (size_t)b * NN * 64;
#pragma unroll 1
  for (int qi = 0; qi < QB / NW; ++qi) {
    int q = w * (QB / NW) + qi;
    int n = scnt[q]; if (n > CAP) n = CAP;
    float4 qq = cp[i0 + q];
    float eqx = rfl(-0.5f * qq.x), eqy = rfl(-0.5f * qq.y);
    float eqz = rfl(-0.5f * qq.z), eqw = rfl(qq.w);
    u64 v = ~0ull;
    if (lane < n) {
      int c = (int)survj[q][lane];
      float4 cj = cp[c];                         // scattered L2 re-load (few)
      float de = dist_exact(eqx, eqy, eqz, eqw,
                            -0.5f * cj.x, -0.5f * cj.y, -0.5f * cj.z, cj.w);
      u32 f = __float_as_uint(de);
      u32 m32 = f ^ ((u32)(((int)f) >> 31) | 0x80000000u);
      v = ((u64)m32 << 32) | (u32)c;
    }
    v = bitonic64(v, lane);
    if (n > 64) {                                // overflow chunk (n<=96)
      u64 v2 = ~0ull;
      if (lane + 64 < n) {
        int c = (int)survj[q][lane + 64];
        float4 cj = cp[c];
        float de = dist_exact(eqx, eqy, eqz, eqw,
                              -0.5f * cj.x, -0.5f * cj.y, -0.5f * cj.z, cj.w);
        u32 f = __float_as_uint(de);
        u32 m32 = f ^ ((u32)(((int)f) >> 31) | 0x80000000u);
        v2 = ((u64)m32 << 32) | (u32)c;
      }
      v2 = bitonic64(v2, lane);
      // R3 FIX: shfl must be executed by ALL lanes (reading an inactive lane's
      // register is undefined -> returned 0 -> zero-keys won the merge sort).
      u64 s2 = shfl_u64(v2, (lane + 48) & 63);   // = v2[lane-16] for lanes 16..31
      u64 vm = (lane < 16) ? v : ((lane < 32) ? s2 : ~0ull);
      v = bitonic64(vm, lane);                   // 16 smallest of union
    }
    if (lane < 16) sidx[q][lane] = (int)(v & 0xFFFFFFFFull);
  }

#pragma unroll 1
  for (int qi = 0; qi < QB / NW; ++qi) {
    int q = w * (QB / NW) + qi;
    const int* id = sidx[q];                     // same-wave LDS, program-order safe
    float m = -3.402823466e+38f;
#pragma unroll
    for (int k = 0; k < 16; ++k)
      m = fmaxf(m, zb[(size_t)id[k] * 64 + lane]);   // coalesced 256B row
    ys[lane][q] = m;
  }
  __syncthreads();   // transpose for coalesced float4 store
  {
    int o = t >> 3;                // 512 threads: 64 rows x 8 float4
    int ql0 = (t & 7) * 4;
    float4 vv;
    vv.x = ys[o][ql0]; vv.y = ys[o][ql0 + 1];
    vv.z = ys[o][ql0 + 2]; vv.w = ys[o][ql0 + 3];
    *(float4*)&y[((size_t)b * 64 + o) * NN + i0 + ql0] = vv;
  }
}

extern "C" void kernel_launch(void* const* d_in, const int* in_sizes, int n_in,
                              void* d_out, int out_size, void* d_ws, size_t ws_size,
                              hipStream_t stream) {
  const float* x      = (const float*)d_in[0];   // [B,64,N]
  const float* coords = (const float*)d_in[1];   // [B,3,N]
  const float* W      = (const float*)d_in[2];   // [64,64]
  float* y = (float*)d_out;                      // [B,64,N] then coords

  char* ws = (char*)d_ws;
  float4*   c4p = (float4*)ws;                   // 512 KB exact (-2x,-2y,-2z,sq)
  _Float16* bfr = (_Float16*)(ws + (512u << 10));// 1 MB  MFMA B-fragments (32 B/cand)
  float*    z   = (float*)(ws + (2u << 20));     // 8 MB  zmat

  float* ycoords = y + (size_t)BB * 64 * NN;

  fused_prep_zmat<<<512 + 128, 256, 0, stream>>>(x, W, coords, z, c4p, bfr, ycoords);
  knn_gather<<<BB * NN / QB, 512, 0, stream>>>(c4p, bfr, z, y);
}

// Round 5
// 130.107 us; speedup vs baseline: 1.3239x; 1.0520x over previous
//
#include <hip/hip_runtime.h>

#define BB 4
#define NN 8192
#define QB 32           // queries per block = one 32x32 MFMA tile of queries
#define NW 8            // waves per block; each scans NN/NW = 1024 candidates
#define CAP 96          // survivor capacity (full-sample threshold -> ~19 expected)
#define SLACK 6e-3f     // >= 2*E_filter; covers f16-subnormal-flush worst case

typedef unsigned long long u64;
typedef unsigned int u32;
typedef _Float16 f16x8 __attribute__((ext_vector_type(8)));
typedef float f32x16 __attribute__((ext_vector_type(16)));

__device__ __forceinline__ u64 shfl_xor_u64(u64 v, int m) {
  u32 lo = (u32)v, hi = (u32)(v >> 32);
  lo = (u32)__shfl_xor((int)lo, m, 64);
  hi = (u32)__shfl_xor((int)hi, m, 64);
  return ((u64)hi << 32) | lo;
}
__device__ __forceinline__ u64 shfl_u64(u64 v, int src) {
  u32 lo = (u32)v, hi = (u32)(v >> 32);
  lo = (u32)__shfl((int)lo, src, 64);
  hi = (u32)__shfl((int)hi, src, 64);
  return ((u64)hi << 32) | lo;
}
__device__ __forceinline__ u64 min_u64(u64 a, u64 b) { return a < b ? a : b; }
// force wave-uniform value into an SGPR
__device__ __forceinline__ float rfl(float x) {
  return __int_as_float(__builtin_amdgcn_readfirstlane(__float_as_int(x)));
}

// ascending 64-lane bitonic sort of u64 keys (slow path only)
__device__ __forceinline__ u64 bitonic64(u64 v, int lane) {
#pragma unroll
  for (int k = 2; k <= 64; k <<= 1) {
#pragma unroll
    for (int jm = k >> 1; jm >= 1; jm >>= 1) {
      u64 o = shfl_xor_u64(v, jm);
      bool keepmin = ((lane & jm) == 0) == ((lane & k) == 0);
      u64 mn = min_u64(v, o);
      u64 mx = (v < o) ? o : v;
      v = keepmin ? mn : mx;
    }
  }
  return v;
}

// ascending 64-lane bitonic sort of u32 VALUES only (1 bpermute + 3 VALU/stage)
__device__ __forceinline__ u32 bitonic32v(u32 v, int lane) {
#pragma unroll
  for (int k = 2; k <= 64; k <<= 1) {
#pragma unroll
    for (int jm = k >> 1; jm >= 1; jm >>= 1) {
      u32 o = (u32)__shfl_xor((int)v, jm, 64);
      bool keepmin = ((lane & jm) == 0) == ((lane & k) == 0);
      v = keepmin ? (v < o ? v : o) : (v < o ? o : v);
    }
  }
  return v;
}

// np-exact distance (bit-matches reference; fma(-2,..) == t-2*inner exactly)
__device__ __forceinline__ float dist_exact(float qx, float qy, float qz, float qw,
                                            float cx, float cy, float cz, float cw) {
#pragma clang fp contract(off)
  float inner = qx * cx;
  inner = inner + qy * cy;
  inner = inner + qz * cz;
  float tt = qw + cw;
  return __builtin_fmaf(-2.0f, inner, tt);
}

// ---- fused: zmat (blocks 0..511, register-blocked 4o x 4j) + coords prep (512..639) ----
__global__ void __launch_bounds__(256, 4) fused_prep_zmat(
    const float* __restrict__ x, const float* __restrict__ W,
    const float* __restrict__ coords,
    float* __restrict__ z, float4* __restrict__ c4p,
    _Float16* __restrict__ bfr,
    float* __restrict__ ycoords) {
#pragma clang fp contract(off)
  __shared__ float Wst[64 * 68];   // [c][o], pitch 68 (16B-aligned rows, bank-spread)
  __shared__ float xs[64 * 64];    // [c][j]
  int t = threadIdx.x;
  if (blockIdx.x < 512) {
    int blk = blockIdx.x;
    int b = blk >> 7;                 // 128 blocks per batch
    int j0 = (blk & 127) * 64;
    for (int r = t; r < 4096; r += 256) Wst[(r & 63) * 68 + (r >> 6)] = W[r];
    const float* xb = x + (size_t)b * 64 * NN;
#pragma unroll
    for (int r = 0; r < 16; ++r) {
      int idx = t + r * 256;
      int c = idx >> 6, j = idx & 63;
      xs[c * 64 + j] = xb[(size_t)c * NN + j0 + j];
    }
    __syncthreads();
    int o0 = (t & 15) * 4, jb = (t >> 4) * 4;
    float4 a0 = {0.f, 0.f, 0.f, 0.f}, a1 = a0, a2 = a0, a3 = a0;  // a[jj].{oi}
#pragma unroll 4
    for (int c = 0; c < 64; ++c) {
      float4 w4 = *(const float4*)&Wst[c * 68 + o0];
      float4 x4 = *(const float4*)&xs[c * 64 + jb];
      a0.x = __builtin_fmaf(w4.x, x4.x, a0.x);
      a0.y = __builtin_fmaf(w4.y, x4.x, a0.y);
      a0.z = __builtin_fmaf(w4.z, x4.x, a0.z);
      a0.w = __builtin_fmaf(w4.w, x4.x, a0.w);
      a1.x = __builtin_fmaf(w4.x, x4.y, a1.x);
      a1.y = __builtin_fmaf(w4.y, x4.y, a1.y);
      a1.z = __builtin_fmaf(w4.z, x4.y, a1.z);
      a1.w = __builtin_fmaf(w4.w, x4.y, a1.w);
      a2.x = __builtin_fmaf(w4.x, x4.z, a2.x);
      a2.y = __builtin_fmaf(w4.y, x4.z, a2.y);
      a2.z = __builtin_fmaf(w4.z, x4.z, a2.z);
      a2.w = __builtin_fmaf(w4.w, x4.z, a2.w);
      a3.x = __builtin_fmaf(w4.x, x4.w, a3.x);
      a3.y = __builtin_fmaf(w4.y, x4.w, a3.y);
      a3.z = __builtin_fmaf(w4.z, x4.w, a3.z);
      a3.w = __builtin_fmaf(w4.w, x4.w, a3.w);
    }
    size_t rbase = (size_t)b * NN + j0 + jb;
    *(float4*)&z[(rbase + 0) * 64 + o0] = a0;
    *(float4*)&z[(rbase + 1) * 64 + o0] = a1;
    *(float4*)&z[(rbase + 2) * 64 + o0] = a2;
    *(float4*)&z[(rbase + 3) * 64 + o0] = a3;
  } else {
    int t2 = (blockIdx.x - 512) * 256 + t;   // [0, B*N) candidates
    int b = t2 >> 13;
    int i = t2 & (NN - 1);
    const float* cb = coords + (size_t)b * 3 * NN;
    float cx = cb[i];
    float cy = cb[NN + i];
    float cz = cb[2 * NN + i];
    float sq = (cx * cx + cy * cy) + cz * cz;   // np-exact sequential fp32
    float4 v; v.x = -2.0f * cx; v.y = -2.0f * cy; v.z = -2.0f * cz; v.w = sq;
    c4p[t2] = v;                                 // exact path (recover x via *-0.5)

    // f16 hi/lo split of (-2x,-2y,-2z,sq) for the MFMA filter
    _Float16 xh = (_Float16)v.x, yh = (_Float16)v.y, zh = (_Float16)v.z;
    _Float16 xl = (_Float16)(v.x - (float)xh);
    _Float16 yl = (_Float16)(v.y - (float)yh);
    _Float16 zl = (_Float16)(v.z - (float)zh);
    _Float16 sh = (_Float16)sq;
    _Float16 sl = (_Float16)(sq - (float)sh);
    f16x8 b0, b1;
    b0[0] = xh; b0[1] = xh; b0[2] = xl; b0[3] = yh;
    b0[4] = yh; b0[5] = yl; b0[6] = zh; b0[7] = zh;
    b1[0] = zl; b1[1] = sh; b1[2] = sl;
    b1[3] = (_Float16)0.f; b1[4] = (_Float16)0.f; b1[5] = (_Float16)0.f;
    b1[6] = (_Float16)0.f; b1[7] = (_Float16)0.f;
    f16x8* bp = (f16x8*)bfr;
    bp[(size_t)t2 * 2]     = b0;
    bp[(size_t)t2 * 2 + 1] = b1;

#pragma unroll
    for (int r = 0; r < 3; ++r)                  // flat coords passthrough
      ycoords[r * (BB * NN) + t2] = coords[r * (BB * NN) + t2];
  }
}

// ---- KNN: block = 32 queries x 8 waves; wave scans 1024 candidates (32 tiles).
// Full-sample pass A (measured free vs half) -> survivors ~19, overflow ~never.
// Epilogue: SELECT the 16-smallest set (order-invariant for the max-gather):
// value-only u32 bitonic -> T15, then ballot/mbcnt compaction. Exact: selected
// set is tie-order-independent when popc(eq)==16-popc(lt); any real tie or
// n>64 drops to the R4-verified u64 sort path (uniform branch, ~never taken).
__global__ void __launch_bounds__(512, 8) knn_gather(const float4* __restrict__ c4p,
                                                     const _Float16* __restrict__ bfr,
                                                     const float* __restrict__ z,
                                                     float* __restrict__ y) {
  __shared__ __align__(16) char pool[QB * 128 * 4];   // 16 KB: wmin (passA) then survj (passB)
  __shared__ float TfL[QB];
  __shared__ int scnt[QB];
  __shared__ int sidx[QB][16];
  __shared__ float ys[64][QB + 1];
  float (*wmin)[128] = (float(*)[128])pool;           // [query][128 subset minima]
  u32 (*survj)[CAP] = (u32(*)[CAP])pool;

  int t = threadIdx.x;
  int w = t >> 6, lane = t & 63;
  int lq = lane & 31, lg = lane >> 5;                 // MFMA col / k-group
  int lg4 = lg << 2;
  int qbase = blockIdx.x * QB;
  int b = qbase >> 13;
  int i0 = qbase & (NN - 1);
  const float4* cp = c4p + (size_t)b * NN;
  int wbase = w * (NN / NW);                          // this wave's candidate range

  if (t < QB) scnt[t] = 0;

  // ---- A fragment: query (l&31), k-slots (l>>5)*8.. (f16 hi/lo split) ----
  float4 qv = cp[i0 + lq];
  float qx = -0.5f * qv.x, qy = -0.5f * qv.y, qz = -0.5f * qv.z;
  _Float16 xh = (_Float16)qx, yh = (_Float16)qy, zh = (_Float16)qz;
  _Float16 xl = (_Float16)(qx - (float)xh);
  _Float16 yl = (_Float16)(qy - (float)yh);
  _Float16 zl = (_Float16)(qz - (float)zh);
  f16x8 af;
  if (lg == 0) {
    af[0] = xh; af[1] = xl; af[2] = xh; af[3] = yh;
    af[4] = yl; af[5] = yh; af[6] = zh; af[7] = zl;
  } else {
    af[0] = zh; af[1] = (_Float16)1.0f; af[2] = (_Float16)1.0f;
    af[3] = (_Float16)0.f; af[4] = (_Float16)0.f; af[5] = (_Float16)0.f;
    af[6] = (_Float16)0.f; af[7] = (_Float16)0.f;
  }

  f32x16 zzz, mn;
#pragma unroll
  for (int r = 0; r < 16; ++r) { zzz[r] = 0.f; mn[r] = 3.402823466e+38f; }

  // per-lane B-fragment stream: candidate = wbase + tt*32 + lq, group lg
  const f16x8* lp = (const f16x8*)bfr + (((size_t)b * NN + wbase + lq) * 2 + lg);

  // ---- pass A (full sample): running min of d~ over all 1024 wave cands ----
  // D[row=query][col=cand]: col = lane&31, row = (reg&3)+8*(reg>>2)+4*(lane>>5)
#pragma unroll 2
  for (int tt = 0; tt < 32; tt += 2) {
    f16x8 bc0 = lp[tt * 64];
    f16x8 bc1 = lp[(tt + 1) * 64];
    f32x16 d0 = __builtin_amdgcn_mfma_f32_32x32x16_f16(af, bc0, zzz, 0, 0, 0);
    f32x16 d1 = __builtin_amdgcn_mfma_f32_32x32x16_f16(af, bc1, zzz, 0, 0, 0);
#pragma unroll
    for (int r = 0; r < 16; ++r) mn[r] = fminf(fminf(mn[r], d0[r]), d1[r]);  // v_min3
  }

  // fold lane pairs (l, l^16): 16 disjoint 64-cand subset-minima per wave/query
#pragma unroll
  for (int r = 0; r < 16; ++r) {
    float m2 = fminf(mn[r], __shfl_xor(mn[r], 16, 64));
    int q = (r & 3) + 8 * (r >> 2) + lg4;
    if (lq < 16) wmin[q][w * 16 + lq] = m2;
  }
  __syncthreads();

  // ---- threshold: pre-min pairs -> 64 subsets of 128 cands; 16th smallest + slack ----
#pragma unroll
  for (int qi = 0; qi < QB / NW; ++qi) {
    int q = w * (QB / NW) + qi;
    float v = fminf(wmin[q][2 * lane], wmin[q][2 * lane + 1]);
#pragma unroll
    for (int k = 2; k <= 64; k <<= 1) {
#pragma unroll
      for (int jm = k >> 1; jm >= 1; jm >>= 1) {
        float o = __shfl_xor(v, jm, 64);
        bool keepmin = ((lane & jm) == 0) == ((lane & k) == 0);
        v = keepmin ? fminf(v, o) : fmaxf(v, o);
      }
    }
    if (lane == 15) TfL[q] = v + SLACK;   // rank-15 = 16th smallest
  }
  __syncthreads();

  // ---- pass B: same MFMA with C = -tf; fire iff d' <= 0 ----
  f32x16 mc;
#pragma unroll
  for (int r = 0; r < 16; ++r) mc[r] = -TfL[(r & 3) + 8 * (r >> 2) + lg4];

#pragma unroll 4
  for (int tt = 0; tt < 32; ++tt) {
    f16x8 bc = lp[tt * 64];
    f32x16 d = __builtin_amdgcn_mfma_f32_32x32x16_f16(af, bc, mc, 0, 0, 0);
    int cand = wbase + tt * 32 + lq;
#pragma unroll
    for (int r = 0; r < 16; ++r) {
      if (d[r] <= 0.f) {
        int q = (r & 3) + 8 * (r >> 2) + lg4;
        int pos = atomicAdd(&scnt[q], 1);
        if (pos < CAP) survj[q][pos] = (u32)cand;
      }
    }
  }
  __syncthreads();

  // ---- epilogue: np-exact keys for survivors; fast SET-select or slow sort ----
  const float* zb = z + (size_t)b * NN * 64;
#pragma unroll 1
  for (int qi = 0; qi < QB / NW; ++qi) {
    int q = w * (QB / NW) + qi;
    int n = scnt[q]; if (n > CAP) n = CAP;
    float4 qq = cp[i0 + q];
    float eqx = rfl(-0.5f * qq.x), eqy = rfl(-0.5f * qq.y);
    float eqz = rfl(-0.5f * qq.z), eqw = rfl(qq.w);
    u32 m32 = 0xFFFFFFFFu, idxv = 0u;
    if (lane < n) {
      int c = (int)survj[q][lane];
      float4 cj = cp[c];                         // scattered L2 re-load (few)
      float de = dist_exact(eqx, eqy, eqz, eqw,
                            -0.5f * cj.x, -0.5f * cj.y, -0.5f * cj.z, cj.w);
      u32 f = __float_as_uint(de);
      m32 = f ^ ((u32)(((int)f) >> 31) | 0x80000000u);
      idxv = (u32)c;
    }
    // value-only ascending sort -> exact 16th-smallest key
    u32 T15 = (u32)__shfl((int)bitonic32v(m32, lane), 15, 64);
    u64 blt = __ballot(m32 < T15);
    u64 beq = __ballot(m32 == T15);
    int k2 = 16 - __popcll(blt);
    if (n <= 64 && __popcll(beq) == k2) {        // uniform; ~always true
      u64 sel = blt | beq;                       // exactly 16 lanes
      if ((sel >> lane) & 1ull) {
        int slot = __builtin_amdgcn_mbcnt_hi(
            (u32)(sel >> 32), __builtin_amdgcn_mbcnt_lo((u32)sel, 0u));
        sidx[q][slot] = (int)idxv;               // set order irrelevant (max)
      }
    } else {                                     // real tie or n>64: exact sort
      u64 v = (lane < n) ? (((u64)m32 << 32) | idxv) : ~0ull;
      v = bitonic64(v, lane);
      if (n > 64) {
        u64 v2 = ~0ull;
        if (lane + 64 < n) {
          int c = (int)survj[q][lane + 64];
          float4 cj = cp[c];
          float de = dist_exact(eqx, eqy, eqz, eqw,
                                -0.5f * cj.x, -0.5f * cj.y, -0.5f * cj.z, cj.w);
          u32 f = __float_as_uint(de);
          u32 mm = f ^ ((u32)(((int)f) >> 31) | 0x80000000u);
          v2 = ((u64)mm << 32) | (u32)c;
        }
        v2 = bitonic64(v2, lane);
        // uniform-exec shfl (R3 lesson: no reads from inactive lanes)
        u64 s2 = shfl_u64(v2, (lane + 48) & 63); // = v2[lane-16] for lanes 16..31
        u64 vm = (lane < 16) ? v : ((lane < 32) ? s2 : ~0ull);
        v = bitonic64(vm, lane);                 // 16 smallest of union
      }
      if (lane < 16) sidx[q][lane] = (int)(v & 0xFFFFFFFFull);
    }
  }

  // ---- gather: 16 z-rows per query, batched loads + associative fmax tree ----
#pragma unroll 2
  for (int qi = 0; qi < QB / NW; ++qi) {
    int q = w * (QB / NW) + qi;
    const int* id = sidx[q];                     // same-wave LDS, program-order safe
    float vv[16];
#pragma unroll
    for (int k = 0; k < 16; ++k)
      vv[k] = zb[(size_t)id[k] * 64 + lane];     // coalesced 256B rows, 16 in flight
#pragma unroll
    for (int s = 8; s >= 1; s >>= 1)
#pragma unroll
      for (int k = 0; k < s; ++k) vv[k] = fmaxf(vv[k], vv[k + s]);
    ys[lane][q] = vv[0];
  }
  __syncthreads();   // transpose for coalesced float4 store
  {
    int o = t >> 3;                // 512 threads: 64 rows x 8 float4
    int ql0 = (t & 7) * 4;
    float4 vv;
    vv.x = ys[o][ql0]; vv.y = ys[o][ql0 + 1];
    vv.z = ys[o][ql0 + 2]; vv.w = ys[o][ql0 + 3];
    *(float4*)&y[((size_t)b * 64 + o) * NN + i0 + ql0] = vv;
  }
}

extern "C" void kernel_launch(void* const* d_in, const int* in_sizes, int n_in,
                              void* d_out, int out_size, void* d_ws, size_t ws_size,
                              hipStream_t stream) {
  const float* x      = (const float*)d_in[0];   // [B,64,N]
  const float* coords = (const float*)d_in[1];   // [B,3,N]
  const float* W      = (const float*)d_in[2];   // [64,64]
  float* y = (float*)d_out;                      // [B,64,N] then coords

  char* ws = (char*)d_ws;
  float4*   c4p = (float4*)ws;                   // 512 KB exact (-2x,-2y,-2z,sq)
  _Float16* bfr = (_Float16*)(ws + (512u << 10));// 1 MB  MFMA B-fragments (32 B/cand)
  float*    z   = (float*)(ws + (2u << 20));     // 8 MB  zmat

  float* ycoords = y + (size_t)BB * 64 * NN;

  fused_prep_zmat<<<512 + 128, 256, 0, stream>>>(x, W, coords, z, c4p, bfr, ycoords);
  knn_gather<<<BB * NN / QB, 512, 0, stream>>>(c4p, bfr, z, y);
}